// Round 2
// baseline (394.975 us; speedup 1.0000x reference)
//
#include <hip/hip_runtime.h>

// PolarQuant: y = FWHT(x*signs)/sqrt(D); idx = searchsorted(mid(centroids), y);
// x_hat = FWHT(centroids[idx])/sqrt(D) * signs.   D=128, BATCH=262144, K=16.
//
// Layout: d_out[0 .. B*D)     = x_hat (f32)
//         d_out[B*D .. 2*B*D) = indices stored as float values (tuple read as f32)
//
// Structure (round 2): 16 contiguous elements per LANE, 8 lanes per row,
// 8 rows per wave. FWHT stages h=1,2,4,8 are register-only; h=16,32,64 are
// __shfl_xor(lane^{1,2,4}) with 16 independent shuffles in flight per stage
// (latency pipelined, vs 2-deep in round 1). Cross-lane butterfly is
// fmaf(+-1, v, o) — exact, bit-identical to the reference's a+b / a-b.

#define D_DIM 128
#define BATCH_N 262144
#define K_LVL 16

// float32 of 1.0/np.sqrt(128.0)
#define INV_SQRT_D 0.08838834764831843f

__global__ __launch_bounds__(256, 4) void polar_quant_kernel(
    const float* __restrict__ x,      // [BATCH, D]
    const float* __restrict__ signs,  // [D]
    const float* __restrict__ cent,   // [K]
    float* __restrict__ out)          // [2*BATCH*D]
{
    __shared__ float s_cent[K_LVL];
    const int tid = threadIdx.x;
    if (tid < K_LVL) s_cent[tid] = cent[tid];

    // Quantization boundaries (uniform -> scalar regs). Same f32 op order as ref.
    float b[K_LVL - 1];
#pragma unroll
    for (int j = 0; j < K_LVL - 1; ++j) b[j] = 0.5f * (cent[j] + cent[j + 1]);

    const int lane = tid & 63;
    const int c = lane & 7;        // chunk index within row: elements [16c,16c+16)
    const int rsub = lane >> 3;    // row within the wave's 8-row group
    const int waves_per_block = blockDim.x >> 6;
    const int gwave = blockIdx.x * waves_per_block + (tid >> 6);
    const int total_waves = gridDim.x * waves_per_block;

    // Per-lane signs for this lane's 16 elements (uniform across rows).
    float sg[16];
    {
        const float4* sp = reinterpret_cast<const float4*>(signs) + c * 4;
#pragma unroll
        for (int k = 0; k < 4; ++k) {
            float4 s4 = sp[k];
            sg[4 * k + 0] = s4.x; sg[4 * k + 1] = s4.y;
            sg[4 * k + 2] = s4.z; sg[4 * k + 3] = s4.w;
        }
    }

    __syncthreads();

    const int total_iters = BATCH_N / 8;   // 8 rows per wave-iteration

    for (int it = gwave; it < total_iters; it += total_waves) {
        const int row = it * 8 + rsub;
        // float4 index of this lane's first element
        const size_t f4base = (size_t)row * (D_DIM / 4) + c * 4;

        float v[16];
        {
            const float4* xp = reinterpret_cast<const float4*>(x) + f4base;
#pragma unroll
            for (int k = 0; k < 4; ++k) {
                float4 L = xp[k];
                v[4 * k + 0] = L.x * sg[4 * k + 0];
                v[4 * k + 1] = L.y * sg[4 * k + 1];
                v[4 * k + 2] = L.z * sg[4 * k + 2];
                v[4 * k + 3] = L.w * sg[4 * k + 3];
            }
        }

        // ---- FWHT #1 ----
        // local stages h=1,2,4,8 (register butterflies, same order as reference)
#pragma unroll
        for (int h = 1; h <= 8; h <<= 1) {
#pragma unroll
            for (int i = 0; i < 16; ++i) {
                if ((i & h) == 0) {
                    float a = v[i] + v[i + h];
                    float s = v[i] - v[i + h];
                    v[i] = a; v[i + h] = s;
                }
            }
        }
        // cross-lane stages h=16,32,64 -> lane xor 1,2,4 (within 8-lane row group)
#pragma unroll
        for (int m = 1; m <= 4; m <<= 1) {
            const float s = (lane & m) ? -1.0f : 1.0f;
#pragma unroll
            for (int i = 0; i < 16; ++i) {
                float o = __shfl_xor(v[i], m, 64);
                v[i] = fmaf(s, v[i], o);   // lower: v+o ; upper: o-v  (exact)
            }
        }

        // ---- quantize ----
        float fi[16];
#pragma unroll
        for (int i = 0; i < 16; ++i) {
            float y = v[i] * INV_SQRT_D;
            int id = 0;
#pragma unroll
            for (int j = 0; j < K_LVL - 1; ++j) id += (y > b[j]) ? 1 : 0;
            fi[i] = (float)id;
            v[i] = s_cent[id];    // 16 distinct words -> broadcast, conflict-free
        }

        // ---- FWHT #2 (unrotate) ----
#pragma unroll
        for (int h = 1; h <= 8; h <<= 1) {
#pragma unroll
            for (int i = 0; i < 16; ++i) {
                if ((i & h) == 0) {
                    float a = v[i] + v[i + h];
                    float s = v[i] - v[i + h];
                    v[i] = a; v[i + h] = s;
                }
            }
        }
#pragma unroll
        for (int m = 1; m <= 4; m <<= 1) {
            const float s = (lane & m) ? -1.0f : 1.0f;
#pragma unroll
            for (int i = 0; i < 16; ++i) {
                float o = __shfl_xor(v[i], m, 64);
                v[i] = fmaf(s, v[i], o);
            }
        }

        // ---- stores ----
        {
            float4* op = reinterpret_cast<float4*>(out) + f4base;
#pragma unroll
            for (int k = 0; k < 4; ++k) {
                float4 S;
                S.x = v[4 * k + 0] * INV_SQRT_D * sg[4 * k + 0];
                S.y = v[4 * k + 1] * INV_SQRT_D * sg[4 * k + 1];
                S.z = v[4 * k + 2] * INV_SQRT_D * sg[4 * k + 2];
                S.w = v[4 * k + 3] * INV_SQRT_D * sg[4 * k + 3];
                op[k] = S;
            }
            float4* ip = reinterpret_cast<float4*>(out)
                       + (size_t)BATCH_N * (D_DIM / 4) + f4base;
#pragma unroll
            for (int k = 0; k < 4; ++k) {
                float4 I;
                I.x = fi[4 * k + 0]; I.y = fi[4 * k + 1];
                I.z = fi[4 * k + 2]; I.w = fi[4 * k + 3];
                ip[k] = I;
            }
        }
    }
}

extern "C" void kernel_launch(void* const* d_in, const int* in_sizes, int n_in,
                              void* d_out, int out_size, void* d_ws, size_t ws_size,
                              hipStream_t stream) {
    const float* x     = (const float*)d_in[0];
    const float* signs = (const float*)d_in[1];
    const float* cent  = (const float*)d_in[2];
    float* out = (float*)d_out;

    // 2048 blocks x 256 threads = 8192 waves; 32768 wave-iterations total
    // (8 rows each) -> 4 iterations per wave, grid-stride.
    dim3 grid(2048), block(256);
    hipLaunchKernelGGL(polar_quant_kernel, grid, block, 0, stream,
                       x, signs, cent, out);
}

// Round 4
// 358.586 us; speedup vs baseline: 1.1015x; 1.1015x over previous
//
#include <hip/hip_runtime.h>

// PolarQuant: y = FWHT(x*signs)/sqrt(D); idx = searchsorted(mid(centroids), y);
// x_hat = FWHT(centroids[idx])/sqrt(D) * signs.   D=128, BATCH=262144, K=16.
//
// Layout: d_out[0 .. B*D)     = x_hat (f32)
//         d_out[B*D .. 2*B*D) = indices stored as float values
//
// Round 3 (resubmit; R3 bench was a GPU-acquisition timeout):
// bit-permuted ownership for coalescing + register-FWHT.
//   element index e (7 bits): bits 0-1 = within-float4 (register)
//                             bits 2-4 = lane (c = lane&7)
//                             bits 5-6 = k (register, float4 #c+8k)
//   -> every load/store instruction k: 8-lane group reads/writes 128 B
//      contiguous per row (fully coalesced, 16 segments/instr),
//   -> FWHT stages h=1,2 and h=32,64 register-local; h=4,8,16 are
//      __shfl_xor masks 1,2,4. Stages executed in reference order
//      h=1..64 with identical a+b / a-b pairing => bit-exact.

#define D_DIM 128
#define BATCH_N 262144
#define K_LVL 16

// float32 of 1.0/np.sqrt(128.0)
#define INV_SQRT_D 0.08838834764831843f

__global__ __launch_bounds__(256, 4) void polar_quant_kernel(
    const float* __restrict__ x,      // [BATCH, D]
    const float* __restrict__ signs,  // [D]
    const float* __restrict__ cent,   // [K]
    float* __restrict__ out)          // [2*BATCH*D]
{
    __shared__ float s_cent[K_LVL];
    const int tid = threadIdx.x;
    if (tid < K_LVL) s_cent[tid] = cent[tid];

    // Quantization boundaries (uniform -> scalar regs). Same f32 op order as ref.
    float b[K_LVL - 1];
#pragma unroll
    for (int j = 0; j < K_LVL - 1; ++j) b[j] = 0.5f * (cent[j] + cent[j + 1]);

    const int lane = tid & 63;
    const int c = lane & 7;        // element bits 2-4
    const int rsub = lane >> 3;    // row within the wave's 8-row group
    const int waves_per_block = blockDim.x >> 6;
    const int gwave = blockIdx.x * waves_per_block + (tid >> 6);
    const int total_waves = gridDim.x * waves_per_block;

    // Per-lane signs: v[i] holds element e = (k<<5)|(c<<2)|w, i = 4k+w.
    float sg[16];
    {
        const float4* sp = reinterpret_cast<const float4*>(signs);
#pragma unroll
        for (int k = 0; k < 4; ++k) {
            float4 s4 = sp[c + 8 * k];
            sg[4 * k + 0] = s4.x; sg[4 * k + 1] = s4.y;
            sg[4 * k + 2] = s4.z; sg[4 * k + 3] = s4.w;
        }
    }

    __syncthreads();

    const int total_iters = BATCH_N / 8;   // 8 rows per wave-iteration

    for (int it = gwave; it < total_iters; it += total_waves) {
        const int row = it * 8 + rsub;
        const size_t rbase = (size_t)row * (D_DIM / 4);   // float4 row base

        float v[16];
        {
            const float4* xp = reinterpret_cast<const float4*>(x) + rbase;
#pragma unroll
            for (int k = 0; k < 4; ++k) {
                float4 L = xp[c + 8 * k];
                v[4 * k + 0] = L.x * sg[4 * k + 0];
                v[4 * k + 1] = L.y * sg[4 * k + 1];
                v[4 * k + 2] = L.z * sg[4 * k + 2];
                v[4 * k + 3] = L.w * sg[4 * k + 3];
            }
        }

        // ---- FWHT #1, stages in reference order ----
        // h=1 (e bit 0 -> i bit 0), h=2 (e bit 1 -> i bit 1): register
#pragma unroll
        for (int h = 1; h <= 2; h <<= 1) {
#pragma unroll
            for (int i = 0; i < 16; ++i) {
                if ((i & h) == 0) {
                    float a = v[i] + v[i + h];
                    float s = v[i] - v[i + h];
                    v[i] = a; v[i + h] = s;
                }
            }
        }
        // h=4,8,16 (e bits 2-4 -> lane bits 0-2): shuffle masks 1,2,4
#pragma unroll
        for (int m = 1; m <= 4; m <<= 1) {
            const float s = (lane & m) ? -1.0f : 1.0f;
#pragma unroll
            for (int i = 0; i < 16; ++i) {
                float o = __shfl_xor(v[i], m, 64);
                v[i] = fmaf(s, v[i], o);   // lower: v+o ; upper: o-v (exact)
            }
        }
        // h=32,64 (e bits 5-6 -> i bits 2-3): register
#pragma unroll
        for (int h = 4; h <= 8; h <<= 1) {
#pragma unroll
            for (int i = 0; i < 16; ++i) {
                if ((i & h) == 0) {
                    float a = v[i] + v[i + h];
                    float s = v[i] - v[i + h];
                    v[i] = a; v[i + h] = s;
                }
            }
        }

        // ---- quantize ----
        float fi[16];
#pragma unroll
        for (int i = 0; i < 16; ++i) {
            float y = v[i] * INV_SQRT_D;
            int id = 0;
#pragma unroll
            for (int j = 0; j < K_LVL - 1; ++j) id += (y > b[j]) ? 1 : 0;
            fi[i] = (float)id;
            v[i] = s_cent[id];    // 16 words -> one per bank, conflict-free
        }

        // store indices now: overlaps with FWHT #2 compute
        {
            float4* ip = reinterpret_cast<float4*>(out)
                       + (size_t)BATCH_N * (D_DIM / 4) + rbase;
#pragma unroll
            for (int k = 0; k < 4; ++k) {
                float4 I;
                I.x = fi[4 * k + 0]; I.y = fi[4 * k + 1];
                I.z = fi[4 * k + 2]; I.w = fi[4 * k + 3];
                ip[c + 8 * k] = I;
            }
        }

        // ---- FWHT #2 (unrotate), same stage order ----
#pragma unroll
        for (int h = 1; h <= 2; h <<= 1) {
#pragma unroll
            for (int i = 0; i < 16; ++i) {
                if ((i & h) == 0) {
                    float a = v[i] + v[i + h];
                    float s = v[i] - v[i + h];
                    v[i] = a; v[i + h] = s;
                }
            }
        }
#pragma unroll
        for (int m = 1; m <= 4; m <<= 1) {
            const float s = (lane & m) ? -1.0f : 1.0f;
#pragma unroll
            for (int i = 0; i < 16; ++i) {
                float o = __shfl_xor(v[i], m, 64);
                v[i] = fmaf(s, v[i], o);
            }
        }
#pragma unroll
        for (int h = 4; h <= 8; h <<= 1) {
#pragma unroll
            for (int i = 0; i < 16; ++i) {
                if ((i & h) == 0) {
                    float a = v[i] + v[i + h];
                    float s = v[i] - v[i + h];
                    v[i] = a; v[i + h] = s;
                }
            }
        }

        // ---- store x_hat ----
        {
            float4* op = reinterpret_cast<float4*>(out) + rbase;
#pragma unroll
            for (int k = 0; k < 4; ++k) {
                float4 S;
                S.x = v[4 * k + 0] * INV_SQRT_D * sg[4 * k + 0];
                S.y = v[4 * k + 1] * INV_SQRT_D * sg[4 * k + 1];
                S.z = v[4 * k + 2] * INV_SQRT_D * sg[4 * k + 2];
                S.w = v[4 * k + 3] * INV_SQRT_D * sg[4 * k + 3];
                op[c + 8 * k] = S;
            }
        }
    }
}

extern "C" void kernel_launch(void* const* d_in, const int* in_sizes, int n_in,
                              void* d_out, int out_size, void* d_ws, size_t ws_size,
                              hipStream_t stream) {
    const float* x     = (const float*)d_in[0];
    const float* signs = (const float*)d_in[1];
    const float* cent  = (const float*)d_in[2];
    float* out = (float*)d_out;

    // 2048 blocks x 256 threads = 8192 waves; 32768 wave-iterations total
    // (8 rows each) -> 4 iterations per wave, grid-stride.
    dim3 grid(2048), block(256);
    hipLaunchKernelGGL(polar_quant_kernel, grid, block, 0, stream,
                       x, signs, cent, out);
}

// Round 5
// 355.610 us; speedup vs baseline: 1.1107x; 1.0084x over previous
//
#include <hip/hip_runtime.h>

// PolarQuant: y = FWHT(x*signs)/sqrt(D); idx = searchsorted(mid(centroids), y);
// x_hat = FWHT(centroids[idx])/sqrt(D) * signs.   D=128, BATCH=262144, K=16.
//
// Layout: d_out[0 .. B*D)     = x_hat (f32)
//         d_out[B*D .. 2*B*D) = indices stored as float values
//
// Round 5: one-shot waves + DPP shuffles + register diet.
//   element index e (7 bits): bits 0-1 = within-float4 (register i bits 0-1)
//                             bits 2-4 = lane bits 0-2 (c = lane&7)
//                             bits 5-6 = register i bits 2-3 (float4 #c+8k)
//   FWHT stage order h=1,2,4,8,16,32,64 identical to reference:
//     h=1,2   : register butterflies (i bits 0,1)
//     h=4     : lane xor 1 -> v_mov_dpp quad_perm 0xB1 (VALU, no LDS)
//     h=8     : lane xor 2 -> v_mov_dpp quad_perm 0x4E (VALU, no LDS)
//     h=16    : lane xor 4 -> ds_swizzle BitMode 0x101F (1 DS instr, no addr reg)
//     h=32,64 : register butterflies (i bits 2,3)
//   Cross-lane butterfly = fmaf(+-1, v, o): exact, bit-identical to a+b / a-b.
//   8192 blocks x 256 threads, each wave processes exactly one 8-row tile
//   (no grid-stride loop -> no loop-carried serialization; MLP from turnover).

#define D_DIM 128
#define BATCH_N 262144
#define K_LVL 16

// float32 of 1.0/np.sqrt(128.0)
#define INV_SQRT_D 0.08838834764831843f

template <int CTRL>
__device__ __forceinline__ float dpp_mov(float x) {
    return __uint_as_float((unsigned)__builtin_amdgcn_mov_dpp(
        (int)__float_as_uint(x), CTRL, 0xF, 0xF, false));
}

__device__ __forceinline__ float swz_xor4(float x) {
    // ds_swizzle BitMode: offset = (xor_mask<<10)|(or<<5)|and = (4<<10)|0x1F
    return __uint_as_float((unsigned)__builtin_amdgcn_ds_swizzle(
        (int)__float_as_uint(x), 0x101F));
}

__device__ __forceinline__ void fwht16(float* v, int lane) {
    // h=1, h=2 (element bits 0,1 -> i bits 0,1): register
#pragma unroll
    for (int h = 1; h <= 2; h <<= 1) {
#pragma unroll
        for (int i = 0; i < 16; ++i) {
            if ((i & h) == 0) {
                float a = v[i] + v[i + h];
                float s = v[i] - v[i + h];
                v[i] = a; v[i + h] = s;
            }
        }
    }
    // h=4: lane xor 1 via DPP quad_perm(1,0,3,2)
    {
        const float s = (lane & 1) ? -1.0f : 1.0f;
#pragma unroll
        for (int i = 0; i < 16; ++i) {
            float o = dpp_mov<0xB1>(v[i]);
            v[i] = fmaf(s, v[i], o);   // lower: v+o ; upper: o-v (exact)
        }
    }
    // h=8: lane xor 2 via DPP quad_perm(2,3,0,1)
    {
        const float s = (lane & 2) ? -1.0f : 1.0f;
#pragma unroll
        for (int i = 0; i < 16; ++i) {
            float o = dpp_mov<0x4E>(v[i]);
            v[i] = fmaf(s, v[i], o);
        }
    }
    // h=16: lane xor 4 via ds_swizzle
    {
        const float s = (lane & 4) ? -1.0f : 1.0f;
#pragma unroll
        for (int i = 0; i < 16; ++i) {
            float o = swz_xor4(v[i]);
            v[i] = fmaf(s, v[i], o);
        }
    }
    // h=32, h=64 (element bits 5,6 -> i bits 2,3): register
#pragma unroll
    for (int h = 4; h <= 8; h <<= 1) {
#pragma unroll
        for (int i = 0; i < 16; ++i) {
            if ((i & h) == 0) {
                float a = v[i] + v[i + h];
                float s = v[i] - v[i + h];
                v[i] = a; v[i + h] = s;
            }
        }
    }
}

__global__ __launch_bounds__(256, 6) void polar_quant_kernel(
    const float* __restrict__ x,      // [BATCH, D]
    const float* __restrict__ signs,  // [D]
    const float* __restrict__ cent,   // [K]
    float* __restrict__ out)          // [2*BATCH*D]
{
    __shared__ float s_cent[K_LVL];
    const int tid = threadIdx.x;
    if (tid < K_LVL) s_cent[tid] = cent[tid];

    // Quantization boundaries (uniform; cent loads are scalar). Ref op order.
    float b[K_LVL - 1];
#pragma unroll
    for (int j = 0; j < K_LVL - 1; ++j) b[j] = 0.5f * (cent[j] + cent[j + 1]);

    const int lane = tid & 63;
    const int c = lane & 7;        // element bits 2-4
    const int rsub = lane >> 3;    // row within this wave's 8-row tile
    const int gwave = blockIdx.x * 4 + (tid >> 6);   // 32768 waves total
    const int row = gwave * 8 + rsub;                // exact cover of BATCH
    const size_t rbase = (size_t)row * (D_DIM / 4);  // float4 row base

    // Per-lane signs: v[i] holds element e = (k<<5)|(c<<2)|w, i = 4k+w.
    float sg[16];
    {
        const float4* sp = reinterpret_cast<const float4*>(signs);
#pragma unroll
        for (int k = 0; k < 4; ++k) {
            float4 s4 = sp[c + 8 * k];
            sg[4 * k + 0] = s4.x; sg[4 * k + 1] = s4.y;
            sg[4 * k + 2] = s4.z; sg[4 * k + 3] = s4.w;
        }
    }

    // Load + apply signs (x * +-1.0 is exact).
    float v[16];
    {
        const float4* xp = reinterpret_cast<const float4*>(x) + rbase;
#pragma unroll
        for (int k = 0; k < 4; ++k) {
            float4 L = xp[c + 8 * k];
            v[4 * k + 0] = L.x * sg[4 * k + 0];
            v[4 * k + 1] = L.y * sg[4 * k + 1];
            v[4 * k + 2] = L.z * sg[4 * k + 2];
            v[4 * k + 3] = L.w * sg[4 * k + 3];
        }
    }

    __syncthreads();   // s_cent ready (placed late to overlap with loads)

    // ---- FWHT #1 ----
    fwht16(v, lane);

    // ---- quantize + store idx + gather centroids, one float4 group at a time
    //      (keeps index registers transient: 4 live instead of 16) ----
    {
        float4* ip = reinterpret_cast<float4*>(out)
                   + (size_t)BATCH_N * (D_DIM / 4) + rbase;
#pragma unroll
        for (int k = 0; k < 4; ++k) {
            float fi[4], q[4];
#pragma unroll
            for (int w = 0; w < 4; ++w) {
                float y = v[4 * k + w] * INV_SQRT_D;
                int id = 0;
#pragma unroll
                for (int j = 0; j < K_LVL - 1; ++j) id += (y > b[j]) ? 1 : 0;
                fi[w] = (float)id;
                q[w] = s_cent[id];   // 16 words, 16 banks -> conflict-free
            }
            ip[c + 8 * k] = make_float4(fi[0], fi[1], fi[2], fi[3]);
            v[4 * k + 0] = q[0]; v[4 * k + 1] = q[1];
            v[4 * k + 2] = q[2]; v[4 * k + 3] = q[3];
        }
    }

    // ---- FWHT #2 (unrotate) ----
    fwht16(v, lane);

    // ---- store x_hat: (v * INV) * sg, both muls exact-order-safe ----
    {
        float4* op = reinterpret_cast<float4*>(out) + rbase;
#pragma unroll
        for (int k = 0; k < 4; ++k) {
            float4 S;
            S.x = v[4 * k + 0] * INV_SQRT_D * sg[4 * k + 0];
            S.y = v[4 * k + 1] * INV_SQRT_D * sg[4 * k + 1];
            S.z = v[4 * k + 2] * INV_SQRT_D * sg[4 * k + 2];
            S.w = v[4 * k + 3] * INV_SQRT_D * sg[4 * k + 3];
            op[c + 8 * k] = S;
        }
    }
}

extern "C" void kernel_launch(void* const* d_in, const int* in_sizes, int n_in,
                              void* d_out, int out_size, void* d_ws, size_t ws_size,
                              hipStream_t stream) {
    const float* x     = (const float*)d_in[0];
    const float* signs = (const float*)d_in[1];
    const float* cent  = (const float*)d_in[2];
    float* out = (float*)d_out;

    // 8192 blocks x 256 threads = 32768 waves, one 8-row tile per wave
    // (exact cover: 32768 * 8 = 262144 rows).
    dim3 grid(8192), block(256);
    hipLaunchKernelGGL(polar_quant_kernel, grid, block, 0, stream,
                       x, signs, cent, out);
}